// Round 1
// baseline (352.174 us; speedup 1.0000x reference)
//
#include <hip/hip_runtime.h>
#include <hip/hip_bf16.h>

typedef __attribute__((ext_vector_type(8))) short short8;
typedef __attribute__((ext_vector_type(4))) float f32x4;

__device__ inline float b2f(unsigned short u) {
    union { unsigned int i; float f; } c; c.i = ((unsigned int)u) << 16; return c.f;
}
__device__ inline unsigned short f2b(float f) {
    __hip_bfloat16 h = __float2bfloat16(f);
    return *reinterpret_cast<unsigned short*>(&h);
}

// async global->LDS, 16 B per lane; LDS dest = wave-uniform base + lane*16
__device__ inline void gl_lds16(const unsigned short* g, unsigned short* ldsbase) {
    __builtin_amdgcn_global_load_lds(
        (const __attribute__((address_space(1))) unsigned int*)(g),
        (__attribute__((address_space(3))) unsigned int*)(ldsbase),
        16, 0, 0);
}

// fp32 -> bf16 conversion, 4 elems/thread
__global__ __launch_bounds__(256) void cvt_f32_bf16(
    const float* __restrict__ src, unsigned short* __restrict__ dst, int n4)
{
    int i = blockIdx.x * 256 + threadIdx.x;
    if (i >= n4) return;
    float4 v = ((const float4*)src)[i];
    union { unsigned short u[4]; unsigned long long ll; } p;
    p.u[0] = f2b(v.x); p.u[1] = f2b(v.y); p.u[2] = f2b(v.z); p.u[3] = f2b(v.w);
    ((unsigned long long*)dst)[i] = p.ll;
}

// weight prep, one dispatch: z<3 -> fp32 [1024,1024] transposed to bf16; z==3 -> plain convert Wv
__global__ __launch_bounds__(256) void cvt_weights4(
    const float* __restrict__ s0, const float* __restrict__ s1, const float* __restrict__ s2,
    const float* __restrict__ s3,
    unsigned short* __restrict__ d0, unsigned short* __restrict__ d1,
    unsigned short* __restrict__ d2, unsigned short* __restrict__ d3)
{
    const int z = blockIdx.z;
    if (z == 3) {
        const int i = (blockIdx.y * 32 + blockIdx.x) * 256 + threadIdx.x;
        float4 v = ((const float4*)s3)[i];
        union { unsigned short u[4]; unsigned long long ll; } p;
        p.u[0] = f2b(v.x); p.u[1] = f2b(v.y); p.u[2] = f2b(v.z); p.u[3] = f2b(v.w);
        ((unsigned long long*)d3)[i] = p.ll;
        return;
    }
    const float* src = z == 0 ? s0 : z == 1 ? s1 : s2;
    unsigned short* dst = z == 0 ? d0 : z == 1 ? d1 : d2;
    __shared__ float tile[32][33];
    const int c0 = blockIdx.x * 32, r0 = blockIdx.y * 32;
    const int tx = threadIdx.x & 31, ty = threadIdx.x >> 5;
    #pragma unroll
    for (int i = ty; i < 32; i += 8)
        tile[i][tx] = src[(long)(r0 + i) * 1024 + c0 + tx];
    __syncthreads();
    #pragma unroll
    for (int i = ty; i < 32; i += 8)
        dst[(long)(c0 + i) * 1024 + r0 + tx] = f2b(tile[tx][i]);
}

// bvo[n] = sum_k bv[k] * Wo[k][n] + bo[n]
__global__ __launch_bounds__(64) void make_bvo(
    const unsigned short* __restrict__ Wot, const float* __restrict__ bv,
    const float* __restrict__ bo, float* __restrict__ bvo)
{
    const int n = blockIdx.x;
    const int lane = threadIdx.x;
    const unsigned short* row = Wot + (long)n * 1024;
    float acc = 0.f;
    #pragma unroll
    for (int pass = 0; pass < 2; pass++) {
        const int k = pass * 512 + lane * 8;
        short8 wv = *(const short8*)(row + k);
        #pragma unroll
        for (int j = 0; j < 8; j++)
            acc += bv[k + j] * b2f((unsigned short)wv[j]);
    }
    #pragma unroll
    for (int off = 32; off > 0; off >>= 1) acc += __shfl_xor(acc, off, 64);
    if (lane == 0) bvo[n] = acc + bo[n];
}

// ---- 128-tile machinery (kept only for the tiny Wvo prep GEMM) ----
#define TILE_DECLS \
    __shared__ __attribute__((aligned(16))) unsigned short As[2 * 128 * 32]; \
    __shared__ __attribute__((aligned(16))) unsigned short Bs[2 * 128 * 32]; \
    const int t = threadIdx.x, lane = t & 63, w = t >> 6; \
    const int wr = w >> 1, wc = w & 1; \
    const int lrow = lane & 15, quad = lane >> 4; \
    f32x4 acc[4][4]; \
    _Pragma("unroll") for (int i = 0; i < 4; i++) \
        _Pragma("unroll") for (int j = 0; j < 4; j++) \
            acc[i][j] = (f32x4){0.f, 0.f, 0.f, 0.f};

#define TILE_KLOOP(gA, lda, gB, ldb, Keff) \
    for (int k0 = 0; k0 < (Keff); k0 += 64) { \
        _Pragma("unroll") for (int p = 0; p < 2; p++) \
            _Pragma("unroll") for (int h = 0; h < 2; h++) { \
                gl_lds16((gA) + (long)h * 16 * (lda) + k0 + p * 32, \
                         &As[p * 4096 + (w * 32 + h * 16) * 32]); \
                gl_lds16((gB) + (long)h * 16 * (ldb) + k0 + p * 32, \
                         &Bs[p * 4096 + (w * 32 + h * 16) * 32]); \
            } \
        __syncthreads(); \
        _Pragma("unroll") for (int p = 0; p < 2; p++) { \
            short8 af[4], bfr[4]; \
            _Pragma("unroll") for (int mi = 0; mi < 4; mi++) \
                af[mi] = *(const short8*)&As[p * 4096 + (wr * 64 + mi * 16 + lrow) * 32 + quad * 8]; \
            _Pragma("unroll") for (int ni = 0; ni < 4; ni++) \
                bfr[ni] = *(const short8*)&Bs[p * 4096 + (wc * 64 + ni * 16 + lrow) * 32 + quad * 8]; \
            _Pragma("unroll") for (int mi = 0; mi < 4; mi++) \
                _Pragma("unroll") for (int ni = 0; ni < 4; ni++) \
                    acc[mi][ni] = __builtin_amdgcn_mfma_f32_16x16x32_bf16( \
                        af[mi], bfr[ni], acc[mi][ni], 0, 0, 0); \
        } \
        __syncthreads(); \
    }

template<bool TRI, bool KCAUSAL, int OMODE>
__global__ __launch_bounds__(256) void gemm128(
    const unsigned short* __restrict__ A, const unsigned short* __restrict__ Bt,
    const float* __restrict__ bias, void* __restrict__ Cv,
    int K, int lda, int ldb, int ldc, long sA, long sB, long sC, float scale)
{
    int bm, bn, bz;
    if (TRI) {
        const int q = blockIdx.x;
        bm = (int)((sqrtf(8.f * q + 1.f) - 1.f) * 0.5f);
        while ((bm + 1) * (bm + 2) / 2 <= q) bm++;
        while (bm * (bm + 1) / 2 > q) bm--;
        bn = q - bm * (bm + 1) / 2;
        bz = blockIdx.y;
    } else {
        bm = KCAUSAL ? (gridDim.x - 1 - blockIdx.x) : blockIdx.x;
        bn = blockIdx.y; bz = blockIdx.z;
    }
    A  += (long)bz * sA;
    Bt += (long)bz * sB;
    const int m0 = bm * 128, n0 = bn * 128;

    TILE_DECLS

    const int Keff = KCAUSAL ? ((bm + 1) * 128 < K ? (bm + 1) * 128 : K) : K;
    const unsigned short* gA = A  + (long)(m0 + w * 32 + (lane >> 2)) * lda + (lane & 3) * 8;
    const unsigned short* gB = Bt + (long)(n0 + w * 32 + (lane >> 2)) * ldb + (lane & 3) * 8;
    TILE_KLOOP(gA, lda, gB, ldb, Keff)

    #pragma unroll
    for (int mi = 0; mi < 4; mi++) {
        const int m = m0 + wr * 64 + mi * 16 + quad * 4;
        #pragma unroll
        for (int ni = 0; ni < 4; ni++) {
            const int n = n0 + wc * 64 + ni * 16 + lrow;
            const float bvl = bias ? bias[n] : 0.f;
            #pragma unroll
            for (int rg = 0; rg < 4; rg++) {
                const float val = acc[mi][ni][rg] * scale + bvl;
                if (OMODE == 1)
                    ((float*)Cv)[(long)bz * sC + (long)(m + rg) * ldc + n] = val;
                else
                    ((unsigned short*)Cv)[(long)bz * sC + (long)(m + rg) * ldc + n] = f2b(val);
            }
        }
    }
}

// ==================== 256x256 8-phase GEMM (T2+T3+T4+T5) ====================
// 512 threads = 8 waves (2M x 4N); per-wave C = 128x64; BK=64; LDS 128 KiB dbuf.
// LDS rows are 128 B; bank-conflict-free via slot ^= (row&7) involution applied
// to the global_load_lds SOURCE (LDS dest stays linear) and to the ds_read addr.

#define G256_SHARED \
    __shared__ __attribute__((aligned(16))) unsigned short As[2][256 * 64]; \
    __shared__ __attribute__((aligned(16))) unsigned short Bs[2][256 * 64];

#define G256_DECLS(Aptr, Bptr, LDA, LDB) \
    const int tid = threadIdx.x, lane = tid & 63, w = tid >> 6; \
    const int wm = w >> 2, wn = w & 3; \
    const int lrow = lane & 15, quad = lane >> 4; \
    const int srow = lane >> 3; \
    const int scol = ((lane & 7) ^ srow) << 3; \
    const int lda_ = (LDA), ldb_ = (LDB); \
    const unsigned short* gA = (Aptr) + (long)(m0 + srow) * lda_ + scol; \
    const unsigned short* gB = (Bptr) + (long)(n0 + srow) * ldb_ + scol; \
    f32x4 acc[8][4]; \
    _Pragma("unroll") for (int i_ = 0; i_ < 8; i_++) \
        _Pragma("unroll") for (int j_ = 0; j_ < 4; j_++) \
            acc[i_][j_] = (f32x4){0.f, 0.f, 0.f, 0.f}; \
    short8 af[4][2], bf[2][2];

// pr: 0=A rows 0-127, 1=A rows 128-255, 2=B rows 0-127, 3=B rows 128-255
// one pair = 2 x gl_lds16/thread = 128 rows (wave covers 8 rows per call)
#define G256_STAGE(pr, kt, b) { \
    _Pragma("unroll") for (int j_ = 0; j_ < 2; j_++) { \
        const int row_ = ((pr) & 1) * 128 + j_ * 64 + w * 8; \
        if ((pr) < 2) gl_lds16(gA + (long)row_ * lda_ + (long)(kt) * 64, &As[(b)][row_ * 64]); \
        else          gl_lds16(gB + (long)row_ * ldb_ + (long)(kt) * 64, &Bs[(b)][row_ * 64]); \
    } }

#define G256_RA(MH, P) \
    _Pragma("unroll") for (int i_ = 0; i_ < 4; i_++) \
        _Pragma("unroll") for (int k_ = 0; k_ < 2; k_++) \
            af[i_][k_] = *(const short8*)&As[(P)][(wm * 128 + ((MH) * 4 + i_) * 16 + lrow) * 64 \
                                                 + (((k_ * 4 + quad) ^ (lrow & 7)) << 3)];
#define G256_RB(NH, P) \
    _Pragma("unroll") for (int j_ = 0; j_ < 2; j_++) \
        _Pragma("unroll") for (int k_ = 0; k_ < 2; k_++) \
            bf[j_][k_] = *(const short8*)&Bs[(P)][(wn * 64 + ((NH) * 2 + j_) * 16 + lrow) * 64 \
                                                 + (((k_ * 4 + quad) ^ (lrow & 7)) << 3)];
#define G256_MFMA(MH, NH) \
    _Pragma("unroll") for (int k_ = 0; k_ < 2; k_++) \
        _Pragma("unroll") for (int i_ = 0; i_ < 4; i_++) \
            _Pragma("unroll") for (int j_ = 0; j_ < 2; j_++) \
                acc[(MH) * 4 + i_][(NH) * 2 + j_] = __builtin_amdgcn_mfma_f32_16x16x32_bf16( \
                    af[i_][k_], bf[j_][k_], acc[(MH) * 4 + i_][(NH) * 2 + j_], 0, 0, 0);

// Schedule per K-tile tt (buf p = tt&1):
//  ph1: read A(mh0)+B(nh0)[buf p]; stage B-lo(tt+1)->p^1 ; MFMA(0,0)
//  ph2: read B(nh1);               stage B-hi(tt+1)->p^1 ; MFMA(0,1)
//  ph3: read A(mh1);                                       MFMA(1,1)
//  ph4: read B(nh0);               stage A-lo+A-hi(tt+2)->p; MFMA(1,0); vmcnt(4)
// Counted vmcnt(4): the 4 newest loads (tt+2's A pairs) stay in flight across
// the tile boundary; lgkmcnt(0) before each closing barrier guarantees all
// reads of a buffer are HW-complete before any wave's later stage overwrites it.
#define G256_RUN(NT) { \
    G256_STAGE(0, 0, 0) G256_STAGE(1, 0, 0) G256_STAGE(2, 0, 0) G256_STAGE(3, 0, 0) \
    if ((NT) > 1) { \
        G256_STAGE(0, 1, 1) G256_STAGE(1, 1, 1) \
        asm volatile("s_waitcnt vmcnt(4)" ::: "memory"); \
    } else { \
        asm volatile("s_waitcnt vmcnt(0)" ::: "memory"); \
    } \
    __builtin_amdgcn_s_barrier(); \
    for (int tt = 0; tt < (NT); tt++) { \
        const int p_ = tt & 1; \
        const bool s1_ = (tt + 1 < (NT)), s2_ = (tt + 2 < (NT)); \
        G256_RA(0, p_) G256_RB(0, p_) \
        if (s1_) G256_STAGE(2, tt + 1, p_ ^ 1) \
        __builtin_amdgcn_s_barrier(); \
        __builtin_amdgcn_s_setprio(1); G256_MFMA(0, 0) __builtin_amdgcn_s_setprio(0); \
        asm volatile("s_waitcnt lgkmcnt(0)" ::: "memory"); \
        __builtin_amdgcn_s_barrier(); \
        G256_RB(1, p_) \
        if (s1_) G256_STAGE(3, tt + 1, p_ ^ 1) \
        __builtin_amdgcn_s_barrier(); \
        __builtin_amdgcn_s_setprio(1); G256_MFMA(0, 1) __builtin_amdgcn_s_setprio(0); \
        asm volatile("s_waitcnt lgkmcnt(0)" ::: "memory"); \
        __builtin_amdgcn_s_barrier(); \
        G256_RA(1, p_) \
        __builtin_amdgcn_s_barrier(); \
        __builtin_amdgcn_s_setprio(1); G256_MFMA(1, 1) __builtin_amdgcn_s_setprio(0); \
        asm volatile("s_waitcnt lgkmcnt(0)" ::: "memory"); \
        __builtin_amdgcn_s_barrier(); \
        G256_RB(0, p_) \
        if (s2_) { G256_STAGE(0, tt + 2, p_) G256_STAGE(1, tt + 2, p_) } \
        __builtin_amdgcn_s_barrier(); \
        __builtin_amdgcn_s_setprio(1); G256_MFMA(1, 0) __builtin_amdgcn_s_setprio(0); \
        asm volatile("s_waitcnt lgkmcnt(0)" ::: "memory"); \
        if (s2_) { asm volatile("s_waitcnt vmcnt(4)" ::: "memory"); } \
        else     { asm volatile("s_waitcnt vmcnt(0)" ::: "memory"); } \
        __builtin_amdgcn_s_barrier(); \
        __builtin_amdgcn_sched_barrier(0); \
    } }

template<bool TRI, bool KCAUSAL, int OMODE>
__global__ __launch_bounds__(512, 2) void gemm256(
    const unsigned short* __restrict__ A, const unsigned short* __restrict__ Bt,
    const float* __restrict__ bias, void* __restrict__ Cv,
    int K, int lda, int ldb, int ldc, long sA, long sB, long sC, float scale)
{
    G256_SHARED
    int bm, bn, bz;
    if (TRI) {
        const int q = blockIdx.x;
        bm = (int)((sqrtf(8.f * q + 1.f) - 1.f) * 0.5f);
        while ((bm + 1) * (bm + 2) / 2 <= q) bm++;
        while (bm * (bm + 1) / 2 > q) bm--;
        bn = q - bm * (bm + 1) / 2;
        bz = blockIdx.y;
    } else {
        bm = KCAUSAL ? (gridDim.x - 1 - (int)blockIdx.x) : blockIdx.x;
        bn = blockIdx.y; bz = blockIdx.z;
    }
    A  += (long)bz * sA;
    Bt += (long)bz * sB;
    const int m0 = bm * 256, n0 = bn * 256;
    const int Keff = KCAUSAL ? ((bm + 1) * 256 < K ? (bm + 1) * 256 : K) : K;
    const int nt = Keff >> 6;

    G256_DECLS(A, Bt, lda, ldb)
    G256_RUN(nt)

    #pragma unroll
    for (int mi = 0; mi < 8; mi++) {
        const int m = m0 + wm * 128 + mi * 16 + quad * 4;
        #pragma unroll
        for (int ni = 0; ni < 4; ni++) {
            const int n = n0 + wn * 64 + ni * 16 + lrow;
            const float bvl = bias ? bias[n] : 0.f;
            #pragma unroll
            for (int rg = 0; rg < 4; rg++) {
                const float val = acc[mi][ni][rg] * scale + bvl;
                if (OMODE == 1)
                    ((float*)Cv)[(long)bz * sC + (long)(m + rg) * ldc + n] = val;
                else
                    ((unsigned short*)Cv)[(long)bz * sC + (long)(m + rg) * ldc + n] = f2b(val);
            }
        }
    }
}

// Fused QKV projection on the 256x256 8-phase core.
__global__ __launch_bounds__(512, 2) void qkv256(
    const unsigned short* __restrict__ A,
    const unsigned short* __restrict__ Wqt, const unsigned short* __restrict__ Wkt,
    const unsigned short* __restrict__ Wvot,
    const float* __restrict__ bq, const float* __restrict__ bk,
    unsigned short* __restrict__ Q, unsigned short* __restrict__ Km,
    unsigned short* __restrict__ Vot)
{
    G256_SHARED
    const int bm = blockIdx.x, by = blockIdx.y;
    const int r = by >> 2, bnn = by & 3;
    const unsigned short* Bt = (r == 0) ? Wqt : (r == 1) ? Wkt : Wvot;
    const float* bias = (r == 0) ? bq : (r == 1) ? bk : nullptr;
    const int m0 = bm * 256, n0 = bnn * 256;

    G256_DECLS(A, Bt, 1024, 1024)
    G256_RUN(16)

    #pragma unroll
    for (int mi = 0; mi < 8; mi++) {
        const int m = m0 + wm * 128 + mi * 16 + quad * 4;
        #pragma unroll
        for (int ni = 0; ni < 4; ni++) {
            const int n = n0 + wn * 64 + ni * 16 + lrow;
            if (r < 2) {
                unsigned short* out = (r == 0) ? Q : Km;
                const float bvl = bias[n];
                #pragma unroll
                for (int rg = 0; rg < 4; rg++)
                    out[(long)(m + rg) * 1024 + n] = f2b(acc[mi][ni][rg] + bvl);
            } else {
                #pragma unroll
                for (int rg = 0; rg < 4; rg++)
                    Vot[(long)n * 8192 + m + rg] = f2b(acc[mi][ni][rg]);
            }
        }
    }
}

// Single-pass causal row softmax. Zero-padding now 256-granular so the
// PV GEMM's per-256-row-tile K cap reads only softmaxed-or-zero values.
__global__ __launch_bounds__(256) void softmax_causal(unsigned short* __restrict__ S)
{
    const long row = blockIdx.x;
    const int i = (int)(row & 2047);
    unsigned short* base = S + row * 2048;
    const int t = threadIdx.x;
    const int padded = ((i >> 8) + 1) << 8;
    const int j0 = t * 8;
    const bool active = j0 < padded;

    __shared__ float red[4];

    float v[8];
    if (active) {
        short8 s8 = *(const short8*)(base + j0);
        #pragma unroll
        for (int jj = 0; jj < 8; jj++)
            v[jj] = (j0 + jj <= i) ? b2f((unsigned short)s8[jj]) : -3.0e38f;
    } else {
        #pragma unroll
        for (int jj = 0; jj < 8; jj++) v[jj] = -3.0e38f;
    }

    float lmax = v[0];
    #pragma unroll
    for (int jj = 1; jj < 8; jj++) lmax = fmaxf(lmax, v[jj]);
    #pragma unroll
    for (int off = 32; off > 0; off >>= 1) lmax = fmaxf(lmax, __shfl_xor(lmax, off, 64));
    if ((t & 63) == 0) red[t >> 6] = lmax;
    __syncthreads();
    const float gmax = fmaxf(fmaxf(red[0], red[1]), fmaxf(red[2], red[3]));
    __syncthreads();

    float lsum = 0.f;
    #pragma unroll
    for (int jj = 0; jj < 8; jj++) {
        v[jj] = (v[jj] > -1.0e37f) ? __expf(v[jj] - gmax) : 0.f;
        lsum += v[jj];
    }
    #pragma unroll
    for (int off = 32; off > 0; off >>= 1) lsum += __shfl_xor(lsum, off, 64);
    if ((t & 63) == 0) red[t >> 6] = lsum;
    __syncthreads();
    const float inv = 1.0f / (red[0] + red[1] + red[2] + red[3]);

    if (active) {
        short8 p8;
        #pragma unroll
        for (int jj = 0; jj < 8; jj++) p8[jj] = (short)f2b(v[jj] * inv);
        *(short8*)(base + j0) = p8;
    }
}

extern "C" void kernel_launch(void* const* d_in, const int* in_sizes, int n_in,
                              void* d_out, int out_size, void* d_ws, size_t ws_size,
                              hipStream_t stream)
{
    const float* x  = (const float*)d_in[0];
    const float* Wq = (const float*)d_in[2];
    const float* bq = (const float*)d_in[3];
    const float* Wk = (const float*)d_in[4];
    const float* bk = (const float*)d_in[5];
    const float* Wv = (const float*)d_in[6];
    const float* bv = (const float*)d_in[7];
    const float* Wo = (const float*)d_in[8];
    const float* bo = (const float*)d_in[9];

    unsigned short* ws = (unsigned short*)d_ws;
    const long XSZ = 8192L * 1024;
    const long WSZ = 1024L * 1024;
    unsigned short* xb   = ws;                // [8192,1024] bf16
    unsigned short* Wqt  = ws + XSZ;          // Wq^T bf16
    unsigned short* Wkt  = Wqt + WSZ;         // Wk^T bf16
    unsigned short* Wot  = Wkt + WSZ;         // Wo^T bf16
    unsigned short* Wvb  = Wot + WSZ;         // Wv bf16 (plain)
    unsigned short* Wvot = Wvb + WSZ;         // (Wv@Wo)^T bf16
    unsigned short* Q    = Wvot + WSZ;        // [8192,1024]
    unsigned short* Km   = Q + XSZ;           // [8192,1024]
    unsigned short* Vot  = Km + XSZ;          // [1024,8192] = (x@Wvo)^T
    unsigned short* S    = Vot + XSZ;         // [4][2048,2048] (S -> P in place)
    float*          bvo  = (float*)(S + 4L * 2048 * 2048);   // [1024] fp32

    const dim3 blk(256);

    cvt_f32_bf16<<<dim3(8192), blk, 0, stream>>>(x, xb, (int)(XSZ / 4));
    cvt_weights4<<<dim3(32, 32, 4), blk, 0, stream>>>(
        Wq, Wk, Wo, Wv, Wqt, Wkt, Wot, Wvb);
    make_bvo    <<<dim3(1024), dim3(64), 0, stream>>>(Wot, bv, bo, bvo);

    // Wvo^T = Wo^T @ Wv^T (tiny; stays on 128-tile path)
    gemm128<false, false, 0><<<dim3(8, 8, 1), blk, 0, stream>>>(
        Wot, Wvb, nullptr, Wvot, 1024, 1024, 1024, 1024, 0, 0, 0, 1.f);

    // fused QKV projection (256x256 8-phase)
    qkv256<<<dim3(32, 12), dim3(512), 0, stream>>>(
        xb, Wqt, Wkt, Wvot, bq, bk, Q, Km, Vot);

    // S = Q K^T / sqrt(D), triangular grid of 256-tiles
    gemm256<true, false, 0><<<dim3(36, 4), dim3(512), 0, stream>>>(
        Q, Km, nullptr, S, 1024, 1024, 1024, 2048,
        2048L * 1024, 2048L * 1024, 2048L * 2048, 0.03125f);

    softmax_causal<<<dim3(4 * 2048), blk, 0, stream>>>(S);

    // out = P @ Vo + bvo  (fp32, final output), causal K cap, heavy tiles first
    gemm256<false, true, 1><<<dim3(8, 4, 4), dim3(512), 0, stream>>>(
        S, Vot, bvo, (float*)d_out, 2048, 2048, 8192, 1024,
        2048L * 2048, 2048, 2048L * 1024, 1.f);
}

// Round 2
// 345.535 us; speedup vs baseline: 1.0192x; 1.0192x over previous
//
#include <hip/hip_runtime.h>
#include <hip/hip_bf16.h>

typedef __attribute__((ext_vector_type(8))) short short8;
typedef __attribute__((ext_vector_type(4))) float f32x4;

__device__ inline float b2f(unsigned short u) {
    union { unsigned int i; float f; } c; c.i = ((unsigned int)u) << 16; return c.f;
}
__device__ inline unsigned short f2b(float f) {
    __hip_bfloat16 h = __float2bfloat16(f);
    return *reinterpret_cast<unsigned short*>(&h);
}

// async global->LDS, 16 B per lane; LDS dest = wave-uniform base + lane*16
__device__ inline void gl_lds16(const unsigned short* g, unsigned short* ldsbase) {
    __builtin_amdgcn_global_load_lds(
        (const __attribute__((address_space(1))) unsigned int*)(g),
        (__attribute__((address_space(3))) unsigned int*)(ldsbase),
        16, 0, 0);
}

// fp32 -> bf16 conversion, 4 elems/thread
__global__ __launch_bounds__(256) void cvt_f32_bf16(
    const float* __restrict__ src, unsigned short* __restrict__ dst, int n4)
{
    int i = blockIdx.x * 256 + threadIdx.x;
    if (i >= n4) return;
    float4 v = ((const float4*)src)[i];
    union { unsigned short u[4]; unsigned long long ll; } p;
    p.u[0] = f2b(v.x); p.u[1] = f2b(v.y); p.u[2] = f2b(v.z); p.u[3] = f2b(v.w);
    ((unsigned long long*)dst)[i] = p.ll;
}

// weight prep, one dispatch: z<3 -> fp32 [1024,1024] transposed to bf16; z==3 -> plain convert Wv
__global__ __launch_bounds__(256) void cvt_weights4(
    const float* __restrict__ s0, const float* __restrict__ s1, const float* __restrict__ s2,
    const float* __restrict__ s3,
    unsigned short* __restrict__ d0, unsigned short* __restrict__ d1,
    unsigned short* __restrict__ d2, unsigned short* __restrict__ d3)
{
    const int z = blockIdx.z;
    if (z == 3) {
        const int i = (blockIdx.y * 32 + blockIdx.x) * 256 + threadIdx.x;
        float4 v = ((const float4*)s3)[i];
        union { unsigned short u[4]; unsigned long long ll; } p;
        p.u[0] = f2b(v.x); p.u[1] = f2b(v.y); p.u[2] = f2b(v.z); p.u[3] = f2b(v.w);
        ((unsigned long long*)d3)[i] = p.ll;
        return;
    }
    const float* src = z == 0 ? s0 : z == 1 ? s1 : s2;
    unsigned short* dst = z == 0 ? d0 : z == 1 ? d1 : d2;
    __shared__ float tile[32][33];
    const int c0 = blockIdx.x * 32, r0 = blockIdx.y * 32;
    const int tx = threadIdx.x & 31, ty = threadIdx.x >> 5;
    #pragma unroll
    for (int i = ty; i < 32; i += 8)
        tile[i][tx] = src[(long)(r0 + i) * 1024 + c0 + tx];
    __syncthreads();
    #pragma unroll
    for (int i = ty; i < 32; i += 8)
        dst[(long)(c0 + i) * 1024 + r0 + tx] = f2b(tile[tx][i]);
}

// bvo[n] = sum_k bv[k] * Wo[k][n] + bo[n]
__global__ __launch_bounds__(64) void make_bvo(
    const unsigned short* __restrict__ Wot, const float* __restrict__ bv,
    const float* __restrict__ bo, float* __restrict__ bvo)
{
    const int n = blockIdx.x;
    const int lane = threadIdx.x;
    const unsigned short* row = Wot + (long)n * 1024;
    float acc = 0.f;
    #pragma unroll
    for (int pass = 0; pass < 2; pass++) {
        const int k = pass * 512 + lane * 8;
        short8 wv = *(const short8*)(row + k);
        #pragma unroll
        for (int j = 0; j < 8; j++)
            acc += bv[k + j] * b2f((unsigned short)wv[j]);
    }
    #pragma unroll
    for (int off = 32; off > 0; off >>= 1) acc += __shfl_xor(acc, off, 64);
    if (lane == 0) bvo[n] = acc + bo[n];
}

// ---- 128-tile machinery (Wvo prep, QK^T, PV) ----
#define TILE_DECLS \
    __shared__ __attribute__((aligned(16))) unsigned short As[2 * 128 * 32]; \
    __shared__ __attribute__((aligned(16))) unsigned short Bs[2 * 128 * 32]; \
    const int t = threadIdx.x, lane = t & 63, w = t >> 6; \
    const int wr = w >> 1, wc = w & 1; \
    const int lrow = lane & 15, quad = lane >> 4; \
    f32x4 acc[4][4]; \
    _Pragma("unroll") for (int i = 0; i < 4; i++) \
        _Pragma("unroll") for (int j = 0; j < 4; j++) \
            acc[i][j] = (f32x4){0.f, 0.f, 0.f, 0.f};

#define TILE_KLOOP(gA, lda, gB, ldb, Keff) \
    for (int k0 = 0; k0 < (Keff); k0 += 64) { \
        _Pragma("unroll") for (int p = 0; p < 2; p++) \
            _Pragma("unroll") for (int h = 0; h < 2; h++) { \
                gl_lds16((gA) + (long)h * 16 * (lda) + k0 + p * 32, \
                         &As[p * 4096 + (w * 32 + h * 16) * 32]); \
                gl_lds16((gB) + (long)h * 16 * (ldb) + k0 + p * 32, \
                         &Bs[p * 4096 + (w * 32 + h * 16) * 32]); \
            } \
        __syncthreads(); \
        _Pragma("unroll") for (int p = 0; p < 2; p++) { \
            short8 af[4], bfr[4]; \
            _Pragma("unroll") for (int mi = 0; mi < 4; mi++) \
                af[mi] = *(const short8*)&As[p * 4096 + (wr * 64 + mi * 16 + lrow) * 32 + quad * 8]; \
            _Pragma("unroll") for (int ni = 0; ni < 4; ni++) \
                bfr[ni] = *(const short8*)&Bs[p * 4096 + (wc * 64 + ni * 16 + lrow) * 32 + quad * 8]; \
            _Pragma("unroll") for (int mi = 0; mi < 4; mi++) \
                _Pragma("unroll") for (int ni = 0; ni < 4; ni++) \
                    acc[mi][ni] = __builtin_amdgcn_mfma_f32_16x16x32_bf16( \
                        af[mi], bfr[ni], acc[mi][ni], 0, 0, 0); \
        } \
        __syncthreads(); \
    }

template<bool TRI, bool KCAUSAL, int OMODE>
__global__ __launch_bounds__(256) void gemm128(
    const unsigned short* __restrict__ A, const unsigned short* __restrict__ Bt,
    const float* __restrict__ bias, void* __restrict__ Cv,
    int K, int lda, int ldb, int ldc, long sA, long sB, long sC, float scale)
{
    int bm, bn, bz;
    if (TRI) {
        const int q = blockIdx.x;
        bm = (int)((sqrtf(8.f * q + 1.f) - 1.f) * 0.5f);
        while ((bm + 1) * (bm + 2) / 2 <= q) bm++;
        while (bm * (bm + 1) / 2 > q) bm--;
        bn = q - bm * (bm + 1) / 2;
        bz = blockIdx.y;
    } else {
        bm = KCAUSAL ? (gridDim.x - 1 - blockIdx.x) : blockIdx.x;
        bn = blockIdx.y; bz = blockIdx.z;
    }
    A  += (long)bz * sA;
    Bt += (long)bz * sB;
    const int m0 = bm * 128, n0 = bn * 128;

    TILE_DECLS

    const int Keff = KCAUSAL ? ((bm + 1) * 128 < K ? (bm + 1) * 128 : K) : K;
    const unsigned short* gA = A  + (long)(m0 + w * 32 + (lane >> 2)) * lda + (lane & 3) * 8;
    const unsigned short* gB = Bt + (long)(n0 + w * 32 + (lane >> 2)) * ldb + (lane & 3) * 8;
    TILE_KLOOP(gA, lda, gB, ldb, Keff)

    #pragma unroll
    for (int mi = 0; mi < 4; mi++) {
        const int m = m0 + wr * 64 + mi * 16 + quad * 4;
        #pragma unroll
        for (int ni = 0; ni < 4; ni++) {
            const int n = n0 + wc * 64 + ni * 16 + lrow;
            const float bvl = bias ? bias[n] : 0.f;
            #pragma unroll
            for (int rg = 0; rg < 4; rg++) {
                const float val = acc[mi][ni][rg] * scale + bvl;
                if (OMODE == 1)
                    ((float*)Cv)[(long)bz * sC + (long)(m + rg) * ldc + n] = val;
                else
                    ((unsigned short*)Cv)[(long)bz * sC + (long)(m + rg) * ldc + n] = f2b(val);
            }
        }
    }
}

// ==================== 256x256 8-phase QKV (T2+T3+T4+T5) ====================
// 512 threads = 8 waves (2M x 4N); per-wave C = 128x64; BK=64; LDS 128 KiB dbuf.
// Swizzle: slot ^= (row&7) applied to the gl_lds SOURCE (LDS stays linear) and
// to the ds_read address -> 0 bank conflicts (verified r1).
// Schedule (fixes vs r1): bare s_waitcnt asm (NO memory clobber), per-phase
// lgkmcnt drains removed, stages issued early (ph1-2) so boundary vmcnt(0) is
// cheap, compile-time buffer index via x2 unroll, no sched_barrier.

#define G256_DECLS(Aptr, Bptr, LDA, LDB) \
    const int tid = threadIdx.x, lane = tid & 63, w = tid >> 6; \
    const int wm = w >> 2, wn = w & 3; \
    const int lrow = lane & 15, quad = lane >> 4; \
    const int srow = lane >> 3; \
    const int scol = ((lane & 7) ^ srow) << 3; \
    const int lda_ = (LDA), ldb_ = (LDB); \
    const unsigned short* gA = (Aptr) + (long)(m0 + srow) * lda_ + scol; \
    const unsigned short* gB = (Bptr) + (long)(n0 + srow) * ldb_ + scol; \
    f32x4 acc[8][4]; \
    _Pragma("unroll") for (int i_ = 0; i_ < 8; i_++) \
        _Pragma("unroll") for (int j_ = 0; j_ < 4; j_++) \
            acc[i_][j_] = (f32x4){0.f, 0.f, 0.f, 0.f}; \
    short8 af[4][2], bf[2][2];

// pr: 0=A rows 0-127, 1=A rows 128-255, 2=B rows 0-127, 3=B rows 128-255
#define G256_STAGE(pr, kt, b) { \
    _Pragma("unroll") for (int j_ = 0; j_ < 2; j_++) { \
        const int row_ = ((pr) & 1) * 128 + j_ * 64 + w * 8; \
        if ((pr) < 2) gl_lds16(gA + (long)row_ * lda_ + (long)(kt) * 64, &As[(b)][row_ * 64]); \
        else          gl_lds16(gB + (long)row_ * ldb_ + (long)(kt) * 64, &Bs[(b)][row_ * 64]); \
    } }

#define G256_RA(MH, P) \
    _Pragma("unroll") for (int i_ = 0; i_ < 4; i_++) \
        _Pragma("unroll") for (int k_ = 0; k_ < 2; k_++) \
            af[i_][k_] = *(const short8*)&As[(P)][(wm * 128 + ((MH) * 4 + i_) * 16 + lrow) * 64 \
                                                 + (((k_ * 4 + quad) ^ (lrow & 7)) << 3)];
#define G256_RB(NH, P) \
    _Pragma("unroll") for (int j_ = 0; j_ < 2; j_++) \
        _Pragma("unroll") for (int k_ = 0; k_ < 2; k_++) \
            bf[j_][k_] = *(const short8*)&Bs[(P)][(wn * 64 + ((NH) * 2 + j_) * 16 + lrow) * 64 \
                                                 + (((k_ * 4 + quad) ^ (lrow & 7)) << 3)];
#define G256_MFMA(MH, NH) \
    _Pragma("unroll") for (int k_ = 0; k_ < 2; k_++) \
        _Pragma("unroll") for (int i_ = 0; i_ < 4; i_++) \
            _Pragma("unroll") for (int j_ = 0; j_ < 2; j_++) \
                acc[(MH) * 4 + i_][(NH) * 2 + j_] = __builtin_amdgcn_mfma_f32_16x16x32_bf16( \
                    af[i_][k_], bf[j_][k_], acc[(MH) * 4 + i_][(NH) * 2 + j_], 0, 0, 0);

// One K-tile = 4 phases. Stages for tile tt+1 (-> buf P^1) all issue in ph1-2;
// boundary waits (lgkmcnt for buffer-overwrite hazard, vmcnt for staged data)
// come once per tile, covering loads issued ~2.5 phases earlier.
#define G256_TILE(P, tt) { \
    const bool pf_ = (tt) + 1 < 16; \
    G256_RA(0, P) G256_RB(0, P) \
    if (pf_) { G256_STAGE(0, (tt) + 1, (P) ^ 1) G256_STAGE(1, (tt) + 1, (P) ^ 1) } \
    __builtin_amdgcn_s_barrier(); \
    __builtin_amdgcn_s_setprio(1); G256_MFMA(0, 0) __builtin_amdgcn_s_setprio(0); \
    __builtin_amdgcn_s_barrier(); \
    G256_RB(1, P) \
    if (pf_) { G256_STAGE(2, (tt) + 1, (P) ^ 1) G256_STAGE(3, (tt) + 1, (P) ^ 1) } \
    __builtin_amdgcn_s_barrier(); \
    __builtin_amdgcn_s_setprio(1); G256_MFMA(0, 1) __builtin_amdgcn_s_setprio(0); \
    __builtin_amdgcn_s_barrier(); \
    G256_RA(1, P) \
    __builtin_amdgcn_s_barrier(); \
    __builtin_amdgcn_s_setprio(1); G256_MFMA(1, 1) __builtin_amdgcn_s_setprio(0); \
    __builtin_amdgcn_s_barrier(); \
    G256_RB(0, P) \
    __builtin_amdgcn_s_barrier(); \
    __builtin_amdgcn_s_setprio(1); G256_MFMA(1, 0) __builtin_amdgcn_s_setprio(0); \
    asm volatile("s_waitcnt lgkmcnt(0)"); \
    asm volatile("s_waitcnt vmcnt(0)"); \
    __builtin_amdgcn_s_barrier(); \
}

// Fused QKV projection on the 256x256 8-phase core. K = 1024 -> NT = 16.
__global__ __launch_bounds__(512, 2) void qkv256(
    const unsigned short* __restrict__ A,
    const unsigned short* __restrict__ Wqt, const unsigned short* __restrict__ Wkt,
    const unsigned short* __restrict__ Wvot,
    const float* __restrict__ bq, const float* __restrict__ bk,
    unsigned short* __restrict__ Q, unsigned short* __restrict__ Km,
    unsigned short* __restrict__ Vot)
{
    __shared__ __attribute__((aligned(16))) unsigned short As[2][256 * 64];
    __shared__ __attribute__((aligned(16))) unsigned short Bs[2][256 * 64];

    const int bm = blockIdx.x, by = blockIdx.y;
    const int r = by >> 2, bnn = by & 3;
    const unsigned short* Bt = (r == 0) ? Wqt : (r == 1) ? Wkt : Wvot;
    const float* bias = (r == 0) ? bq : (r == 1) ? bk : nullptr;
    const int m0 = bm * 256, n0 = bnn * 256;

    G256_DECLS(A, Bt, 1024, 1024)

    // prologue: stage tile 0 into buf0, drain, go
    G256_STAGE(0, 0, 0) G256_STAGE(1, 0, 0) G256_STAGE(2, 0, 0) G256_STAGE(3, 0, 0)
    asm volatile("s_waitcnt vmcnt(0)");
    __builtin_amdgcn_s_barrier();

    #pragma unroll 1
    for (int tt = 0; tt < 16; tt += 2) {
        G256_TILE(0, tt)
        G256_TILE(1, tt + 1)
    }

    #pragma unroll
    for (int mi = 0; mi < 8; mi++) {
        const int m = m0 + wm * 128 + mi * 16 + quad * 4;
        #pragma unroll
        for (int ni = 0; ni < 4; ni++) {
            const int n = n0 + wn * 64 + ni * 16 + lrow;
            if (r < 2) {
                unsigned short* out = (r == 0) ? Q : Km;
                const float bvl = bias[n];
                #pragma unroll
                for (int rg = 0; rg < 4; rg++)
                    out[(long)(m + rg) * 1024 + n] = f2b(acc[mi][ni][rg] + bvl);
            } else {
                #pragma unroll
                for (int rg = 0; rg < 4; rg++)
                    Vot[(long)n * 8192 + m + rg] = f2b(acc[mi][ni][rg]);
            }
        }
    }
}

// Single-pass causal row softmax, 128-granular padding (PV uses 128-tile K cap).
__global__ __launch_bounds__(256) void softmax_causal(unsigned short* __restrict__ S)
{
    const long row = blockIdx.x;
    const int i = (int)(row & 2047);
    unsigned short* base = S + row * 2048;
    const int t = threadIdx.x;
    const int padded = ((i >> 7) + 1) << 7;
    const int j0 = t * 8;
    const bool active = j0 < padded;

    __shared__ float red[4];

    float v[8];
    if (active) {
        short8 s8 = *(const short8*)(base + j0);
        #pragma unroll
        for (int jj = 0; jj < 8; jj++)
            v[jj] = (j0 + jj <= i) ? b2f((unsigned short)s8[jj]) : -3.0e38f;
    } else {
        #pragma unroll
        for (int jj = 0; jj < 8; jj++) v[jj] = -3.0e38f;
    }

    float lmax = v[0];
    #pragma unroll
    for (int jj = 1; jj < 8; jj++) lmax = fmaxf(lmax, v[jj]);
    #pragma unroll
    for (int off = 32; off > 0; off >>= 1) lmax = fmaxf(lmax, __shfl_xor(lmax, off, 64));
    if ((t & 63) == 0) red[t >> 6] = lmax;
    __syncthreads();
    const float gmax = fmaxf(fmaxf(red[0], red[1]), fmaxf(red[2], red[3]));
    __syncthreads();

    float lsum = 0.f;
    #pragma unroll
    for (int jj = 0; jj < 8; jj++) {
        v[jj] = (v[jj] > -1.0e37f) ? __expf(v[jj] - gmax) : 0.f;
        lsum += v[jj];
    }
    #pragma unroll
    for (int off = 32; off > 0; off >>= 1) lsum += __shfl_xor(lsum, off, 64);
    if ((t & 63) == 0) red[t >> 6] = lsum;
    __syncthreads();
    const float inv = 1.0f / (red[0] + red[1] + red[2] + red[3]);

    if (active) {
        short8 p8;
        #pragma unroll
        for (int jj = 0; jj < 8; jj++) p8[jj] = (short)f2b(v[jj] * inv);
        *(short8*)(base + j0) = p8;
    }
}

extern "C" void kernel_launch(void* const* d_in, const int* in_sizes, int n_in,
                              void* d_out, int out_size, void* d_ws, size_t ws_size,
                              hipStream_t stream)
{
    const float* x  = (const float*)d_in[0];
    const float* Wq = (const float*)d_in[2];
    const float* bq = (const float*)d_in[3];
    const float* Wk = (const float*)d_in[4];
    const float* bk = (const float*)d_in[5];
    const float* Wv = (const float*)d_in[6];
    const float* bv = (const float*)d_in[7];
    const float* Wo = (const float*)d_in[8];
    const float* bo = (const float*)d_in[9];

    unsigned short* ws = (unsigned short*)d_ws;
    const long XSZ = 8192L * 1024;
    const long WSZ = 1024L * 1024;
    unsigned short* xb   = ws;                // [8192,1024] bf16
    unsigned short* Wqt  = ws + XSZ;          // Wq^T bf16
    unsigned short* Wkt  = Wqt + WSZ;         // Wk^T bf16
    unsigned short* Wot  = Wkt + WSZ;         // Wo^T bf16
    unsigned short* Wvb  = Wot + WSZ;         // Wv bf16 (plain)
    unsigned short* Wvot = Wvb + WSZ;         // (Wv@Wo)^T bf16
    unsigned short* Q    = Wvot + WSZ;        // [8192,1024]
    unsigned short* Km   = Q + XSZ;           // [8192,1024]
    unsigned short* Vot  = Km + XSZ;          // [1024,8192] = (x@Wvo)^T
    unsigned short* S    = Vot + XSZ;         // [4][2048,2048] (S -> P in place)
    float*          bvo  = (float*)(S + 4L * 2048 * 2048);   // [1024] fp32

    const dim3 blk(256);

    cvt_f32_bf16<<<dim3(8192), blk, 0, stream>>>(x, xb, (int)(XSZ / 4));
    cvt_weights4<<<dim3(32, 32, 4), blk, 0, stream>>>(
        Wq, Wk, Wo, Wv, Wqt, Wkt, Wot, Wvb);
    make_bvo    <<<dim3(1024), dim3(64), 0, stream>>>(Wot, bv, bo, bvo);

    // Wvo^T = Wo^T @ Wv^T (tiny; 128-tile path)
    gemm128<false, false, 0><<<dim3(8, 8, 1), blk, 0, stream>>>(
        Wot, Wvb, nullptr, Wvot, 1024, 1024, 1024, 1024, 0, 0, 0, 1.f);

    // fused QKV projection (256x256 8-phase, fixed waits)
    qkv256<<<dim3(32, 12), dim3(512), 0, stream>>>(
        xb, Wqt, Wkt, Wvot, bq, bk, Q, Km, Vot);

    // S = Q K^T / sqrt(D), triangular grid (proven 128-tile path)
    gemm128<true, false, 0><<<dim3(136, 4), blk, 0, stream>>>(
        Q, Km, nullptr, S, 1024, 1024, 1024, 2048,
        2048L * 1024, 2048L * 1024, 2048L * 2048, 0.03125f);

    softmax_causal<<<dim3(4 * 2048), blk, 0, stream>>>(S);

    // out = P @ Vo + bvo  (fp32, final output), causal K cap, heavy tiles first
    gemm128<false, true, 1><<<dim3(16, 8, 4), blk, 0, stream>>>(
        S, Vot, bvo, (float*)d_out, 2048, 2048, 8192, 1024,
        2048L * 2048, 2048, 2048L * 1024, 1.f);
}

// Round 3
// 338.387 us; speedup vs baseline: 1.0407x; 1.0211x over previous
//
#include <hip/hip_runtime.h>
#include <hip/hip_bf16.h>

typedef __attribute__((ext_vector_type(8))) short short8;
typedef __attribute__((ext_vector_type(4))) float f32x4;

__device__ inline float b2f(unsigned short u) {
    union { unsigned int i; float f; } c; c.i = ((unsigned int)u) << 16; return c.f;
}
__device__ inline unsigned short f2b(float f) {
    __hip_bfloat16 h = __float2bfloat16(f);
    return *reinterpret_cast<unsigned short*>(&h);
}

// async global->LDS, 16 B per lane; LDS dest = wave-uniform base + lane*16
__device__ inline void gl_lds16(const unsigned short* g, unsigned short* ldsbase) {
    __builtin_amdgcn_global_load_lds(
        (const __attribute__((address_space(1))) unsigned int*)(g),
        (__attribute__((address_space(3))) unsigned int*)(ldsbase),
        16, 0, 0);
}

// ---- merged prep: weights transpose/convert + x convert + bvo, ONE dispatch ----
// grid (32,32,7): z 0-2 transpose {Wq,Wk,Wo}->bf16^T; z=3 convert Wv; z=4,5 convert x;
// z=6 (y==0 only): bvo[n] = sum_k bv[k]*Wo[k][n] + bo[n] from fp32 Wo.
__global__ __launch_bounds__(256) void prep(
    const float* __restrict__ x,
    const float* __restrict__ Wq, const float* __restrict__ Wk,
    const float* __restrict__ Wo, const float* __restrict__ Wv,
    const float* __restrict__ bv, const float* __restrict__ bo,
    unsigned short* __restrict__ xb,
    unsigned short* __restrict__ Wqt, unsigned short* __restrict__ Wkt,
    unsigned short* __restrict__ Wot, unsigned short* __restrict__ Wvb,
    float* __restrict__ bvo)
{
    const int z = blockIdx.z;
    const int t = threadIdx.x;
    __shared__ float tile[32][33];

    if (z < 3) {
        const float* src = z == 0 ? Wq : z == 1 ? Wk : Wo;
        unsigned short* dst = z == 0 ? Wqt : z == 1 ? Wkt : Wot;
        const int c0 = blockIdx.x * 32, r0 = blockIdx.y * 32;
        const int tx = t & 31, ty = t >> 5;
        #pragma unroll
        for (int i = ty; i < 32; i += 8)
            tile[i][tx] = src[(long)(r0 + i) * 1024 + c0 + tx];
        __syncthreads();
        #pragma unroll
        for (int i = ty; i < 32; i += 8)
            dst[(long)(c0 + i) * 1024 + r0 + tx] = f2b(tile[tx][i]);
        return;
    }
    if (z == 3) {
        const int i = (blockIdx.y * 32 + blockIdx.x) * 256 + t;
        float4 v = ((const float4*)Wv)[i];
        union { unsigned short u[4]; unsigned long long ll; } p;
        p.u[0] = f2b(v.x); p.u[1] = f2b(v.y); p.u[2] = f2b(v.z); p.u[3] = f2b(v.w);
        ((unsigned long long*)Wvb)[i] = p.ll;
        return;
    }
    if (z < 6) {
        const int bl = (z - 4) * 1024 + blockIdx.y * 32 + blockIdx.x;
        #pragma unroll
        for (int k = 0; k < 4; k++) {
            const int i = bl * 1024 + k * 256 + t;
            float4 v = ((const float4*)x)[i];
            union { unsigned short u[4]; unsigned long long ll; } p;
            p.u[0] = f2b(v.x); p.u[1] = f2b(v.y); p.u[2] = f2b(v.z); p.u[3] = f2b(v.w);
            ((unsigned long long*)xb)[i] = p.ll;
        }
        return;
    }
    // z == 6: bvo. Only y==0 blocks work; block x handles n in [x*32, x*32+32).
    if (blockIdx.y != 0) return;
    const int tx = t & 31, ty = t >> 5;
    const int n = blockIdx.x * 32 + tx;
    float acc = 0.f;
    #pragma unroll 4
    for (int j = 0; j < 128; j++) {
        const int k = ty * 128 + j;
        acc += Wo[(long)k * 1024 + n] * bv[k];
    }
    float* red = &tile[0][0];  // reuse: 8x32 floats
    red[ty * 32 + tx] = acc;
    __syncthreads();
    if (ty == 0) {
        float s = 0.f;
        #pragma unroll
        for (int j = 0; j < 8; j++) s += red[j * 32 + tx];
        bvo[n] = s + bo[n];
    }
}

// ---- 128-tile K-loop body (shared by gemm128 and qkv_proj) ----
#define TILE_KLOOP(As, Bs, gA, lda, gB, ldb, Keff) \
    for (int k0 = 0; k0 < (Keff); k0 += 64) { \
        _Pragma("unroll") for (int p = 0; p < 2; p++) \
            _Pragma("unroll") for (int h = 0; h < 2; h++) { \
                gl_lds16((gA) + (long)h * 16 * (lda) + k0 + p * 32, \
                         &(As)[p * 4096 + (w * 32 + h * 16) * 32]); \
                gl_lds16((gB) + (long)h * 16 * (ldb) + k0 + p * 32, \
                         &(Bs)[p * 4096 + (w * 32 + h * 16) * 32]); \
            } \
        __syncthreads(); \
        _Pragma("unroll") for (int p = 0; p < 2; p++) { \
            short8 af[4], bfr[4]; \
            _Pragma("unroll") for (int mi = 0; mi < 4; mi++) \
                af[mi] = *(const short8*)&(As)[p * 4096 + (wr * 64 + mi * 16 + lrow) * 32 + quad * 8]; \
            _Pragma("unroll") for (int ni = 0; ni < 4; ni++) \
                bfr[ni] = *(const short8*)&(Bs)[p * 4096 + (wc * 64 + ni * 16 + lrow) * 32 + quad * 8]; \
            _Pragma("unroll") for (int mi = 0; mi < 4; mi++) \
                _Pragma("unroll") for (int ni = 0; ni < 4; ni++) \
                    acc[mi][ni] = __builtin_amdgcn_mfma_f32_16x16x32_bf16( \
                        af[mi], bfr[ni], acc[mi][ni], 0, 0, 0); \
        } \
        __syncthreads(); \
    }

#define TILE_DECLS \
    const int t = threadIdx.x, lane = t & 63, w = t >> 6; \
    const int wr = w >> 1, wc = w & 1; \
    const int lrow = lane & 15, quad = lane >> 4; \
    f32x4 acc[4][4]; \
    _Pragma("unroll") for (int i = 0; i < 4; i++) \
        _Pragma("unroll") for (int j = 0; j < 4; j++) \
            acc[i][j] = (f32x4){0.f, 0.f, 0.f, 0.f};

template<bool TRI, bool KCAUSAL, int OMODE>
__global__ __launch_bounds__(256) void gemm128(
    const unsigned short* __restrict__ A, const unsigned short* __restrict__ Bt,
    const float* __restrict__ bias, void* __restrict__ Cv,
    int K, int lda, int ldb, int ldc, long sA, long sB, long sC, float scale)
{
    __shared__ __attribute__((aligned(16))) unsigned short As[2 * 128 * 32];
    __shared__ __attribute__((aligned(16))) unsigned short Bs[2 * 128 * 32];
    int bm, bn, bz;
    if (TRI) {
        const int q = blockIdx.x;
        bm = (int)((sqrtf(8.f * q + 1.f) - 1.f) * 0.5f);
        while ((bm + 1) * (bm + 2) / 2 <= q) bm++;
        while (bm * (bm + 1) / 2 > q) bm--;
        bn = q - bm * (bm + 1) / 2;
        bz = blockIdx.y;
    } else {
        bm = KCAUSAL ? (gridDim.x - 1 - blockIdx.x) : blockIdx.x;
        bn = blockIdx.y; bz = blockIdx.z;
    }
    A  += (long)bz * sA;
    Bt += (long)bz * sB;
    const int m0 = bm * 128, n0 = bn * 128;

    TILE_DECLS

    const int Keff = KCAUSAL ? ((bm + 1) * 128 < K ? (bm + 1) * 128 : K) : K;
    const unsigned short* gA = A  + (long)(m0 + w * 32 + (lane >> 2)) * lda + (lane & 3) * 8;
    const unsigned short* gB = Bt + (long)(n0 + w * 32 + (lane >> 2)) * ldb + (lane & 3) * 8;
    TILE_KLOOP(As, Bs, gA, lda, gB, ldb, Keff)

    #pragma unroll
    for (int mi = 0; mi < 4; mi++) {
        const int m = m0 + wr * 64 + mi * 16 + quad * 4;
        #pragma unroll
        for (int ni = 0; ni < 4; ni++) {
            const int n = n0 + wc * 64 + ni * 16 + lrow;
            const float bvl = bias ? bias[n] : 0.f;
            #pragma unroll
            for (int rg = 0; rg < 4; rg++) {
                const float val = acc[mi][ni][rg] * scale + bvl;
                if (OMODE == 1)
                    ((float*)Cv)[(long)bz * sC + (long)(m + rg) * ldc + n] = val;
                else
                    ((unsigned short*)Cv)[(long)bz * sC + (long)(m + rg) * ldc + n] = f2b(val);
            }
        }
    }
}

// Fused QKV projection, 128-tile structure, LDS-transposed coalesced epilogues.
// pool (32 KiB) carves As+Bs during the K-loop, then is reused as the 128x128
// bf16 output tile for coalesced stores (Vot: XOR-swizzled transpose).
__global__ __launch_bounds__(256) void qkv_proj(
    const unsigned short* __restrict__ A,
    const unsigned short* __restrict__ Wqt, const unsigned short* __restrict__ Wkt,
    const unsigned short* __restrict__ Wvot,
    const float* __restrict__ bq, const float* __restrict__ bk,
    unsigned short* __restrict__ Q, unsigned short* __restrict__ Km,
    unsigned short* __restrict__ Vot)
{
    __shared__ __attribute__((aligned(16))) unsigned short pool[16384];  // 32 KiB
    unsigned short* As = pool;
    unsigned short* Bs = pool + 8192;

    const int bm = blockIdx.x, by = blockIdx.y;
    const int r = by >> 3, bnn = by & 7;
    const unsigned short* Bt = (r == 0) ? Wqt : (r == 1) ? Wkt : Wvot;
    const float* bias = (r == 0) ? bq : (r == 1) ? bk : nullptr;
    const int m0 = bm * 128, n0 = bnn * 128;

    TILE_DECLS

    const unsigned short* gA = A  + (long)(m0 + w * 32 + (lane >> 2)) * 1024 + (lane & 3) * 8;
    const unsigned short* gB = Bt + (long)(n0 + w * 32 + (lane >> 2)) * 1024 + (lane & 3) * 8;
    TILE_KLOOP(As, Bs, gA, 1024, gB, 1024, 1024)
    // loop's final __syncthreads: all LDS reads done -> pool reusable

    if (r < 2) {
        // pool[m][n] linear, then coalesced 256-B row stores
        #pragma unroll
        for (int mi = 0; mi < 4; mi++) {
            #pragma unroll
            for (int ni = 0; ni < 4; ni++) {
                const int n_l = wc * 64 + ni * 16 + lrow;
                const float bvl = bias[n0 + n_l];
                #pragma unroll
                for (int rg = 0; rg < 4; rg++) {
                    const int m_l = wr * 64 + mi * 16 + quad * 4 + rg;
                    pool[m_l * 128 + n_l] = f2b(acc[mi][ni][rg] + bvl);
                }
            }
        }
        __syncthreads();
        unsigned short* out = (r == 0) ? Q : Km;
        #pragma unroll
        for (int it = 0; it < 8; it++) {
            const int idx = it * 256 + t;
            const int m_l = idx >> 4, c = idx & 15;
            short8 v = *(const short8*)&pool[m_l * 128 + c * 8];
            *(short8*)&out[(long)(m0 + m_l) * 1024 + n0 + c * 8] = v;
        }
    } else {
        // transposed: pool[n][m ^ ((n&15)<<3)] (XOR keeps rg-quads contiguous and
        // spreads the 256-B row stride across banks), then coalesced Vot rows.
        #pragma unroll
        for (int mi = 0; mi < 4; mi++) {
            #pragma unroll
            for (int ni = 0; ni < 4; ni++) {
                const int n_l = wc * 64 + ni * 16 + lrow;
                const int mb = wr * 64 + mi * 16 + quad * 4;
                union { unsigned short u[4]; unsigned long long ll; } pk;
                #pragma unroll
                for (int rg = 0; rg < 4; rg++) pk.u[rg] = f2b(acc[mi][ni][rg]);
                *(unsigned long long*)&pool[n_l * 128 + (mb ^ ((n_l & 15) << 3))] = pk.ll;
            }
        }
        __syncthreads();
        #pragma unroll
        for (int it = 0; it < 8; it++) {
            const int idx = it * 256 + t;
            const int n_l = idx >> 4, c = idx & 15;
            short8 v = *(const short8*)&pool[n_l * 128 + ((c * 8) ^ ((n_l & 15) << 3))];
            *(short8*)&Vot[(long)(n0 + n_l) * 8192 + m0 + c * 8] = v;
        }
    }
}

// Single-pass causal row softmax, 128-granular padding (PV uses 128-tile K cap).
__global__ __launch_bounds__(256) void softmax_causal(unsigned short* __restrict__ S)
{
    const long row = blockIdx.x;
    const int i = (int)(row & 2047);
    unsigned short* base = S + row * 2048;
    const int t = threadIdx.x;
    const int padded = ((i >> 7) + 1) << 7;
    const int j0 = t * 8;
    const bool active = j0 < padded;

    __shared__ float red[4];

    float v[8];
    if (active) {
        short8 s8 = *(const short8*)(base + j0);
        #pragma unroll
        for (int jj = 0; jj < 8; jj++)
            v[jj] = (j0 + jj <= i) ? b2f((unsigned short)s8[jj]) : -3.0e38f;
    } else {
        #pragma unroll
        for (int jj = 0; jj < 8; jj++) v[jj] = -3.0e38f;
    }

    float lmax = v[0];
    #pragma unroll
    for (int jj = 1; jj < 8; jj++) lmax = fmaxf(lmax, v[jj]);
    #pragma unroll
    for (int off = 32; off > 0; off >>= 1) lmax = fmaxf(lmax, __shfl_xor(lmax, off, 64));
    if ((t & 63) == 0) red[t >> 6] = lmax;
    __syncthreads();
    const float gmax = fmaxf(fmaxf(red[0], red[1]), fmaxf(red[2], red[3]));
    __syncthreads();

    float lsum = 0.f;
    #pragma unroll
    for (int jj = 0; jj < 8; jj++) {
        v[jj] = (v[jj] > -1.0e37f) ? __expf(v[jj] - gmax) : 0.f;
        lsum += v[jj];
    }
    #pragma unroll
    for (int off = 32; off > 0; off >>= 1) lsum += __shfl_xor(lsum, off, 64);
    if ((t & 63) == 0) red[t >> 6] = lsum;
    __syncthreads();
    const float inv = 1.0f / (red[0] + red[1] + red[2] + red[3]);

    if (active) {
        short8 p8;
        #pragma unroll
        for (int jj = 0; jj < 8; jj++) p8[jj] = (short)f2b(v[jj] * inv);
        *(short8*)(base + j0) = p8;
    }
}

extern "C" void kernel_launch(void* const* d_in, const int* in_sizes, int n_in,
                              void* d_out, int out_size, void* d_ws, size_t ws_size,
                              hipStream_t stream)
{
    const float* x  = (const float*)d_in[0];
    const float* Wq = (const float*)d_in[2];
    const float* bq = (const float*)d_in[3];
    const float* Wk = (const float*)d_in[4];
    const float* bk = (const float*)d_in[5];
    const float* Wv = (const float*)d_in[6];
    const float* bv = (const float*)d_in[7];
    const float* Wo = (const float*)d_in[8];
    const float* bo = (const float*)d_in[9];

    unsigned short* ws = (unsigned short*)d_ws;
    const long XSZ = 8192L * 1024;
    const long WSZ = 1024L * 1024;
    unsigned short* xb   = ws;                // [8192,1024] bf16
    unsigned short* Wqt  = ws + XSZ;          // Wq^T bf16
    unsigned short* Wkt  = Wqt + WSZ;         // Wk^T bf16
    unsigned short* Wot  = Wkt + WSZ;         // Wo^T bf16
    unsigned short* Wvb  = Wot + WSZ;         // Wv bf16 (plain)
    unsigned short* Wvot = Wvb + WSZ;         // (Wv@Wo)^T bf16
    unsigned short* Q    = Wvot + WSZ;        // [8192,1024]
    unsigned short* Km   = Q + XSZ;           // [8192,1024]
    unsigned short* Vot  = Km + XSZ;          // [1024,8192] = (x@Wvo)^T
    unsigned short* S    = Vot + XSZ;         // [4][2048,2048] (S -> P in place)
    float*          bvo  = (float*)(S + 4L * 2048 * 2048);   // [1024] fp32

    const dim3 blk(256);

    // merged prep: weights + x convert + bvo, one dispatch
    prep<<<dim3(32, 32, 7), blk, 0, stream>>>(
        x, Wq, Wk, Wo, Wv, bv, bo, xb, Wqt, Wkt, Wot, Wvb, bvo);

    // Wvo^T = Wo^T @ Wv^T
    gemm128<false, false, 0><<<dim3(8, 8, 1), blk, 0, stream>>>(
        Wot, Wvb, nullptr, Wvot, 1024, 1024, 1024, 1024, 0, 0, 0, 1.f);

    // fused QKV projection (128-tile, coalesced epilogues)
    qkv_proj<<<dim3(64, 24), blk, 0, stream>>>(
        xb, Wqt, Wkt, Wvot, bq, bk, Q, Km, Vot);

    // S = Q K^T / sqrt(D), triangular grid
    gemm128<true, false, 0><<<dim3(136, 4), blk, 0, stream>>>(
        Q, Km, nullptr, S, 1024, 1024, 1024, 2048,
        2048L * 1024, 2048L * 1024, 2048L * 2048, 0.03125f);

    softmax_causal<<<dim3(4 * 2048), blk, 0, stream>>>(S);

    // out = P @ Vo + bvo  (fp32, final output), causal K cap, heavy tiles first
    gemm128<false, true, 1><<<dim3(16, 8, 4), blk, 0, stream>>>(
        S, Vot, bvo, (float*)d_out, 2048, 2048, 8192, 1024,
        2048L * 2048, 2048, 2048L * 1024, 1.f);
}